// Round 14
// baseline (568.385 us; speedup 1.0000x reference)
//
#include <hip/hip_runtime.h>

// Encoder_8718783611479: stateless per-step LSTMCell => one GEMM + elementwise.
//   gates = xt @ W_ih^T (+ b_ih + b_hh), only i,g,o gates live (f * c_prev = 0)
//   out = sigmoid(sigmoid(o_g)*tanh(sigmoid(i_g)*tanh(g_g)))
// xt[b,t,k] = x[b*43200 + k*240 + t]  (K=180 strided, M=t contiguous)
//
// v15 = v12 structure (the reproduced best: ~187us kernel, bench 554) with
// ONLY the block granularity changed: TB 80 -> 48, NP 3 -> 5, grid 10240,
// LDS 30.7 -> 18.4KB. Rationale: v12's symptom is all pipes <35% busy
// (HBM duty 33%, occupancy ~17%) -- too few independent block phases per CU.
// Smaller parts = more resident blocks (wave-slot-capped ~5/CU instead of
// LDS-capped) = more interleaved staging bursts = higher HBM duty.
// Geometry stays clean: out part boundary 48*360B = exactly 135 cache lines
// (write compactness structural); x part sharing grows 2->4 interior lines
// per (b,k) row, proven L3-absorbed (v13: FETCH unchanged under sharing
// remap). All v12 mechanisms byte-identical: per-unit load->cvt->write
// staging (v11 proved hoisting regresses), XOR swizzle, tt-outer per-tile
// MFMA + immediate compact epilogue, realign s_barrier between tiles.
// Pre-registered: if neutral (+-2%), block-TLP is not the limiter; revert
// to v12 as terminal.

#define B_SZ 2048
#define T_SZ 240
#define K_SZ 180
#define H_SZ 90
#define KP   192   // K padded to 6*32
#define TB   48    // t per block
#define NP   5     // parts per batch
#define NTT  3     // 16-row t-tiles per block
#define NU   540   // staging units: 45 k4 x 12 t4

#define WS_B_OFF 110592   // W frags [3][6][6][64]x16B, then [3][96] f32 biases

typedef __bf16 bf16x8 __attribute__((ext_vector_type(8)));
typedef __bf16 bf16x4 __attribute__((ext_vector_type(4)));
typedef float  f32x4  __attribute__((ext_vector_type(4)));

__device__ __forceinline__ float sigmoidf_(float x) {
    return __builtin_amdgcn_rcpf(1.0f + __expf(-x));
}
__device__ __forceinline__ float tanhf_(float x) {
    return 1.0f - 2.0f * __builtin_amdgcn_rcpf(__expf(2.0f * x) + 1.0f);
}

// Even XOR key per row t; granule = 4 bf16 = 8B. Swizzle within 16-granule
// (128B) groups. Even key preserves b128 granule-pair adjacency (so the
// fragment read is one aligned ds_read_b128). Measured conflicts: negligible.
__device__ __forceinline__ int skey(int t) {
    return (2 * (t + (t >> 4))) & 14;
}
__device__ __forceinline__ int sgran(int g, int t) {
    return (g & ~15) | ((g ^ skey(t)) & 15);
}

// ---------------- prepack: W fragments + fused bias into d_ws ----------------
__global__ __launch_bounds__(384) void prepack_kernel(
    const float* __restrict__ W_ih,
    const float* __restrict__ b_ih,
    const float* __restrict__ b_hh,
    void* __restrict__ ws)
{
    __bf16* wp = (__bf16*)ws;
    float*  bp = (float*)((char*)ws + WS_B_OFF);
    const int gb[3] = {0, 180, 270};   // i, g, o row bases in W_ih (4H=360 rows)

    const int bid = blockIdx.x;
    const int tid = threadIdx.x;
    if (bid < 18) {
        const int g  = bid / 6;
        const int ks = bid % 6;
        const int w  = tid >> 6;
        const int l  = tid & 63;
        const int q  = l >> 4;
        const int n  = l & 15;
        const int h  = w * 16 + n;
        bf16x8 f;
        #pragma unroll
        for (int j = 0; j < 8; ++j) {
            int k = ks * 32 + q * 8 + j;
            float v = (h < H_SZ && k < K_SZ) ? W_ih[(size_t)(gb[g] + h) * K_SZ + k] : 0.0f;
            f[j] = (__bf16)v;
        }
        // fragment order: [g][ks][wave][lane] x 16B -> coalesced load in main
        *(bf16x8*)(wp + (size_t)(((g * 6 + ks) * 6 + w) * 64 + l) * 8) = f;
    } else {
        if (tid < 288) {
            int g = tid / 96, hh = tid % 96;
            bp[g * 96 + hh] = (hh < H_SZ) ? (b_ih[gb[g] + hh] + b_hh[gb[g] + hh]) : 0.0f;
        }
    }
}

// ---------------- main kernel ----------------
__global__ __launch_bounds__(384, 3) void lstm_fused_kernel(
    const float* __restrict__ x,
    const void*  __restrict__ ws,
    float* __restrict__ out)
{
    __shared__ __align__(16) __bf16 aBuf[TB * KP];   // 18.4 KB, swizzled [t][k]

    const int bid  = blockIdx.x;
    const int b    = bid / NP;
    const int part = bid - b * NP;
    const int t0   = part * TB;

    const int tid  = threadIdx.x;
    const int wave = tid >> 6;      // 0..5 -> h-tile
    const int lane = tid & 63;
    const int q    = lane >> 4;     // quad 0..3
    const int n    = lane & 15;
    const int h    = wave * 16 + n; // output column; valid if < 90
    const bool hv  = (h < H_SZ);

    const float* xb = x + (size_t)b * (K_SZ * T_SZ) + t0;

    // zero-fill k-padding granules 45..47 of each row (swizzle is a per-row
    // bijection on slots, so zero slots never collide with data slots)
    if (tid < TB * 3) {
        int t  = tid / 3;
        int gz = 45 + (tid - (tid / 3) * 3);
        *(unsigned long long*)(aBuf + t * KP + sgran(gz, t) * 4) = 0ull;
    }

    // ---- one-shot staging: 540 4x4 blocks, register transpose, b64 writes ----
    #pragma unroll
    for (int p = 0; p < 2; ++p) {
        int u = tid + p * 384;
        if (p < 1 || u < NU) {                   // 45 k-granules x 12 t4
            int k4 = u / 12;
            int t4 = u - k4 * 12;
            const float* src = xb + (k4 * 4) * T_SZ + t4 * 4;
            f32x4 r0 = *(const f32x4*)(src);
            f32x4 r1 = *(const f32x4*)(src + T_SZ);
            f32x4 r2 = *(const f32x4*)(src + 2 * T_SZ);
            f32x4 r3 = *(const f32x4*)(src + 3 * T_SZ);
            #pragma unroll
            for (int j = 0; j < 4; ++j) {
                int t = t4 * 4 + j;
                bf16x4 w;
                w[0] = (__bf16)r0[j]; w[1] = (__bf16)r1[j];
                w[2] = (__bf16)r2[j]; w[3] = (__bf16)r3[j];
                *(bf16x4*)(aBuf + t * KP + sgran(k4, t) * 4) = w;
            }
        }
    }

    // ---- W fragments ----
    const bf16x8* wp = (const bf16x8*)ws;
    bf16x8 bfrag[3][6];
    #pragma unroll
    for (int g = 0; g < 3; ++g)
        #pragma unroll
        for (int ks = 0; ks < 6; ++ks)
            bfrag[g][ks] = wp[((g * 6 + ks) * 6 + wave) * 64 + lane];

    const float* bp = (const float*)((const char*)ws + WS_B_OFF);
    const float bias_i = bp[0 * 96 + h];   // h <= 95, zero-padded
    const float bias_g = bp[1 * 96 + h];
    const float bias_o = bp[2 * 96 + h];
    float* ob = out + (size_t)b * (T_SZ * H_SZ) + (size_t)t0 * H_SZ;

    __syncthreads();   // staging complete

    // ---- tt-outer: per-tile MFMA + immediate compact epilogue ----
    #pragma unroll
    for (int tt = 0; tt < NTT; ++tt) {
        f32x4 acc0 = {0.f, 0.f, 0.f, 0.f};
        f32x4 acc1 = {0.f, 0.f, 0.f, 0.f};
        f32x4 acc2 = {0.f, 0.f, 0.f, 0.f};
        const int t = tt * 16 + n;
        #pragma unroll
        for (int ks = 0; ks < 6; ++ks) {
            int g = ks * 8 + 2 * q;            // even granule-pair base
            bf16x8 a = *(const bf16x8*)(aBuf + t * KP + sgran(g, t) * 4);
            acc0 = __builtin_amdgcn_mfma_f32_16x16x32_bf16(a, bfrag[0][ks], acc0, 0, 0, 0);
            acc1 = __builtin_amdgcn_mfma_f32_16x16x32_bf16(a, bfrag[1][ks], acc1, 0, 0, 0);
            acc2 = __builtin_amdgcn_mfma_f32_16x16x32_bf16(a, bfrag[2][ks], acc2, 0, 0, 0);
        }
        // C/D layout: col = lane&15 -> h, row = q*4+e -> t within tile
        if (hv) {
            const int tg = tt * 16 + q * 4;
            #pragma unroll
            for (int e = 0; e < 4; ++e) {
                float gi = acc0[e] + bias_i;
                float gg = acc1[e] + bias_g;
                float go = acc2[e] + bias_o;
                float cc = sigmoidf_(gi) * tanhf_(gg);
                float hh = sigmoidf_(go) * tanhf_(cc);
                ob[(size_t)(tg + e) * H_SZ + h] = sigmoidf_(hh);
            }
        }
        // wave re-alignment only (no data dependency): keeps all 6 waves'
        // stores to each out line within one tile window -> single writeback
        if (tt + 1 < NTT) __builtin_amdgcn_s_barrier();
    }
}

extern "C" void kernel_launch(void* const* d_in, const int* in_sizes, int n_in,
                              void* d_out, int out_size, void* d_ws, size_t ws_size,
                              hipStream_t stream) {
    const float* x    = (const float*)d_in[0];
    const float* W_ih = (const float*)d_in[1];
    // d_in[2] = W_hh: dead (h0 = c0 = 0 at every timestep)
    const float* b_ih = (const float*)d_in[3];
    const float* b_hh = (const float*)d_in[4];
    float* out = (float*)d_out;

    // ~112 KB of workspace: prepacked W fragments + fused biases
    prepack_kernel<<<dim3(19), dim3(384), 0, stream>>>(W_ih, b_ih, b_hh, d_ws);
    lstm_fused_kernel<<<dim3(B_SZ * NP), dim3(384), 0, stream>>>(x, d_ws, out);
}

// Round 15
// 554.471 us; speedup vs baseline: 1.0251x; 1.0251x over previous
//
#include <hip/hip_runtime.h>

// Encoder_8718783611479: stateless per-step LSTMCell => one GEMM + elementwise.
//   gates = xt @ W_ih^T (+ b_ih + b_hh), only i,g,o gates live (f * c_prev = 0)
//   out = sigmoid(sigmoid(o_g)*tanh(sigmoid(i_g)*tanh(g_g)))
// xt[b,t,k] = x[b*43200 + k*240 + t]  (K=180 strided, M=t contiguous)
//
// v16 = TERMINAL: exact v12/v5 (best measured, reproduced: ~187us kernel,
// bench 553.7/555.7). 15-round ledger: every deviation regressed or was
// neutral with a counter-diagnosed cause --
//   schedule: v7 persistent pipeline (scratch spill, +55MB WRITE), v9
//     per-tile pipeline (quanta < HBM latency), v11 load hoist (fought
//     scheduler), v14 2-phase stage (no load hoist materialized);
//   occupancy: v6 streamed-W@(384,5) (W evicted from L2, FETCH +560MB),
//     v8 waves_per_eu(3,3) pin (occupancy clamp, 224us);
//   granularity: v10 single-wave blocks (FETCH+WRITE amplified), v15 TB=48
//     (neutral-negative);
//   locality: v13 XCD co-location (neutral, L3 already absorbs sharing).
// Mechanisms this kernel stands on (all measured):
//   - prepacked W fragments + fused biases in d_ws (fixed the per-wave
//     divergent W gather: v0 472us -> v3 273us)
//   - one-shot swizzled LDS stage, register 4x4 transpose, packed b64
//     writes; per-unit load->cvt->write order (compiler software-pipelines
//     units; explicit hoisting regresses)
//   - tt-outer per-tile MFMA + immediate compact epilogue + realign
//     s_barrier between tiles -> WRITE_SIZE exactly ideal 172.8MB
//   - allocator-chosen ~72-84 VGPR; W remat from L2-hot pack is cheap
// Residual gap to the ~85us traffic floor is the stage->compute phase
// structure's HBM duty cycle (~33%); all in-structure mechanisms for
// raising it were falsified. Converged local optimum.

#define B_SZ 2048
#define T_SZ 240
#define K_SZ 180
#define H_SZ 90
#define KP   192   // K padded to 6*32
#define TB   80    // t per block
#define NP   3     // parts per batch
#define NTT  5     // 16-row t-tiles per block

#define WS_B_OFF 110592   // W frags [3][6][6][64]x16B, then [3][96] f32 biases

typedef __bf16 bf16x8 __attribute__((ext_vector_type(8)));
typedef __bf16 bf16x4 __attribute__((ext_vector_type(4)));
typedef float  f32x4  __attribute__((ext_vector_type(4)));

__device__ __forceinline__ float sigmoidf_(float x) {
    return __builtin_amdgcn_rcpf(1.0f + __expf(-x));
}
__device__ __forceinline__ float tanhf_(float x) {
    return 1.0f - 2.0f * __builtin_amdgcn_rcpf(__expf(2.0f * x) + 1.0f);
}

// Even XOR key per row t; granule = 4 bf16 = 8B. Swizzle within 16-granule
// (128B) groups. Even key preserves b128 granule-pair adjacency (so the
// fragment read is one aligned ds_read_b128). Measured conflicts: negligible.
__device__ __forceinline__ int skey(int t) {
    return (2 * (t + (t >> 4))) & 14;
}
__device__ __forceinline__ int sgran(int g, int t) {
    return (g & ~15) | ((g ^ skey(t)) & 15);
}

// ---------------- prepack: W fragments + fused bias into d_ws ----------------
__global__ __launch_bounds__(384) void prepack_kernel(
    const float* __restrict__ W_ih,
    const float* __restrict__ b_ih,
    const float* __restrict__ b_hh,
    void* __restrict__ ws)
{
    __bf16* wp = (__bf16*)ws;
    float*  bp = (float*)((char*)ws + WS_B_OFF);
    const int gb[3] = {0, 180, 270};   // i, g, o row bases in W_ih (4H=360 rows)

    const int bid = blockIdx.x;
    const int tid = threadIdx.x;
    if (bid < 18) {
        const int g  = bid / 6;
        const int ks = bid % 6;
        const int w  = tid >> 6;
        const int l  = tid & 63;
        const int q  = l >> 4;
        const int n  = l & 15;
        const int h  = w * 16 + n;
        bf16x8 f;
        #pragma unroll
        for (int j = 0; j < 8; ++j) {
            int k = ks * 32 + q * 8 + j;
            float v = (h < H_SZ && k < K_SZ) ? W_ih[(size_t)(gb[g] + h) * K_SZ + k] : 0.0f;
            f[j] = (__bf16)v;
        }
        // fragment order: [g][ks][wave][lane] x 16B -> coalesced load in main
        *(bf16x8*)(wp + (size_t)(((g * 6 + ks) * 6 + w) * 64 + l) * 8) = f;
    } else {
        if (tid < 288) {
            int g = tid / 96, hh = tid % 96;
            bp[g * 96 + hh] = (hh < H_SZ) ? (b_ih[gb[g] + hh] + b_hh[gb[g] + hh]) : 0.0f;
        }
    }
}

// ---------------- main kernel ----------------
__global__ __launch_bounds__(384, 3) void lstm_fused_kernel(
    const float* __restrict__ x,
    const void*  __restrict__ ws,
    float* __restrict__ out)
{
    __shared__ __align__(16) __bf16 aBuf[TB * KP];   // 30.7 KB, swizzled [t][k]

    const int bid  = blockIdx.x;
    const int b    = bid / NP;
    const int part = bid - b * NP;
    const int t0   = part * TB;

    const int tid  = threadIdx.x;
    const int wave = tid >> 6;      // 0..5 -> h-tile
    const int lane = tid & 63;
    const int q    = lane >> 4;     // quad 0..3
    const int n    = lane & 15;
    const int h    = wave * 16 + n; // output column; valid if < 90
    const bool hv  = (h < H_SZ);

    const float* xb = x + (size_t)b * (K_SZ * T_SZ) + t0;

    // zero-fill k-padding granules 45..47 of each row (swizzle is a per-row
    // bijection on slots, so zero slots never collide with data slots)
    if (tid < TB * 3) {
        int t  = tid / 3;
        int gz = 45 + (tid - (tid / 3) * 3);
        *(unsigned long long*)(aBuf + t * KP + sgran(gz, t) * 4) = 0ull;
    }

    // ---- one-shot staging: 900 4x4 blocks, register transpose, b64 writes ----
    #pragma unroll
    for (int p = 0; p < 3; ++p) {
        int u = tid + p * 384;
        if (p < 2 || u < 900) {                  // 45 k-granules x 20 t4
            int k4 = u / 20;
            int t4 = u - k4 * 20;
            const float* src = xb + (k4 * 4) * T_SZ + t4 * 4;
            f32x4 r0 = *(const f32x4*)(src);
            f32x4 r1 = *(const f32x4*)(src + T_SZ);
            f32x4 r2 = *(const f32x4*)(src + 2 * T_SZ);
            f32x4 r3 = *(const f32x4*)(src + 3 * T_SZ);
            #pragma unroll
            for (int j = 0; j < 4; ++j) {
                int t = t4 * 4 + j;
                bf16x4 w;
                w[0] = (__bf16)r0[j]; w[1] = (__bf16)r1[j];
                w[2] = (__bf16)r2[j]; w[3] = (__bf16)r3[j];
                *(bf16x4*)(aBuf + t * KP + sgran(k4, t) * 4) = w;
            }
        }
    }

    // ---- W fragments: loaded once here (allocator remats as it prefers) ----
    const bf16x8* wp = (const bf16x8*)ws;
    bf16x8 bfrag[3][6];
    #pragma unroll
    for (int g = 0; g < 3; ++g)
        #pragma unroll
        for (int ks = 0; ks < 6; ++ks)
            bfrag[g][ks] = wp[((g * 6 + ks) * 6 + wave) * 64 + lane];

    const float* bp = (const float*)((const char*)ws + WS_B_OFF);
    const float bias_i = bp[0 * 96 + h];   // h <= 95, zero-padded
    const float bias_g = bp[1 * 96 + h];
    const float bias_o = bp[2 * 96 + h];
    float* ob = out + (size_t)b * (T_SZ * H_SZ) + (size_t)t0 * H_SZ;

    __syncthreads();   // staging complete

    // ---- tt-outer: per-tile MFMA + immediate compact epilogue ----
    #pragma unroll
    for (int tt = 0; tt < NTT; ++tt) {
        f32x4 acc0 = {0.f, 0.f, 0.f, 0.f};
        f32x4 acc1 = {0.f, 0.f, 0.f, 0.f};
        f32x4 acc2 = {0.f, 0.f, 0.f, 0.f};
        const int t = tt * 16 + n;
        #pragma unroll
        for (int ks = 0; ks < 6; ++ks) {
            int g = ks * 8 + 2 * q;            // even granule-pair base
            bf16x8 a = *(const bf16x8*)(aBuf + t * KP + sgran(g, t) * 4);
            acc0 = __builtin_amdgcn_mfma_f32_16x16x32_bf16(a, bfrag[0][ks], acc0, 0, 0, 0);
            acc1 = __builtin_amdgcn_mfma_f32_16x16x32_bf16(a, bfrag[1][ks], acc1, 0, 0, 0);
            acc2 = __builtin_amdgcn_mfma_f32_16x16x32_bf16(a, bfrag[2][ks], acc2, 0, 0, 0);
        }
        // C/D layout: col = lane&15 -> h, row = q*4+e -> t within tile
        if (hv) {
            const int tg = tt * 16 + q * 4;
            #pragma unroll
            for (int e = 0; e < 4; ++e) {
                float gi = acc0[e] + bias_i;
                float gg = acc1[e] + bias_g;
                float go = acc2[e] + bias_o;
                float cc = sigmoidf_(gi) * tanhf_(gg);
                float hh = sigmoidf_(go) * tanhf_(cc);
                ob[(size_t)(tg + e) * H_SZ + h] = sigmoidf_(hh);
            }
        }
        // wave re-alignment only (no data dependency): keeps all 6 waves'
        // stores to each out line within one tile window -> single writeback
        if (tt + 1 < NTT) __builtin_amdgcn_s_barrier();
    }
}

extern "C" void kernel_launch(void* const* d_in, const int* in_sizes, int n_in,
                              void* d_out, int out_size, void* d_ws, size_t ws_size,
                              hipStream_t stream) {
    const float* x    = (const float*)d_in[0];
    const float* W_ih = (const float*)d_in[1];
    // d_in[2] = W_hh: dead (h0 = c0 = 0 at every timestep)
    const float* b_ih = (const float*)d_in[3];
    const float* b_hh = (const float*)d_in[4];
    float* out = (float*)d_out;

    // ~112 KB of workspace: prepacked W fragments + fused biases
    prepack_kernel<<<dim3(19), dim3(384), 0, stream>>>(W_ih, b_ih, b_hh, d_ws);
    lstm_fused_kernel<<<dim3(B_SZ * NP), dim3(384), 0, stream>>>(x, d_ws, out);
}